// Round 3
// baseline (377.941 us; speedup 1.0000x reference)
//
#include <hip/hip_runtime.h>
#include <hip/hip_bf16.h>

#define KK 32
#define DIN 128
#define DOUT 32
#define NVEC (KK * DOUT)        // 1024 floats per node
#define NV4  (NVEC / 4)         // 256 float4 per node
#define MBKT 64                 // bucket slots per row == wave size
#define OCAP 4096               // overflow capacity (never used for Poisson(16))

typedef float        vf4 __attribute__((ext_vector_type(4)));
typedef unsigned int vu4 __attribute__((ext_vector_type(4)));

__device__ __forceinline__ float bfu2f(unsigned int u) {
    return __uint_as_float(u << 16);
}
__device__ __forceinline__ unsigned int f2bfu(float f) {
    __hip_bfloat16 b = __float2bfloat16(f);
    return *(unsigned short*)&b;
}

// ---------------- K1: h[r][e] = sum_d x[r][d] * W[d][e], store bf16 ----------
// Each thread: 4 rows x 4 cols. Block=256 -> 128 rows/block. grid 2500.
// x loads nontemporal (streamed once; keep L2 for h which agg re-reads 16x).
__global__ __launch_bounds__(256) void gemm_kernel(
    const float* __restrict__ x, const float* __restrict__ w,
    unsigned short* __restrict__ h)
{
    __shared__ vf4 wl4[DIN * DOUT / 4];   // 16 KB
    const int tid = threadIdx.x;
    const vf4* w4 = (const vf4*)w;
    #pragma unroll
    for (int i = tid; i < DIN * DOUT / 4; i += 256) wl4[i] = w4[i];
    __syncthreads();

    const int eg = tid & 7;          // 4-col group
    const int rg = tid >> 3;         // 32 row-groups
    const int r0 = blockIdx.x * 128 + rg * 4;

    const vf4* x0 = (const vf4*)(x + (size_t)r0 * DIN);  // 4 rows, 32 vf4 each
    float acc[4][4];
    #pragma unroll
    for (int a = 0; a < 4; ++a)
        #pragma unroll
        for (int b = 0; b < 4; ++b) acc[a][b] = 0.f;

    #pragma unroll 2
    for (int d4 = 0; d4 < DIN / 4; ++d4) {
        vf4 wv0 = wl4[(d4 * 4 + 0) * 8 + eg];
        vf4 wv1 = wl4[(d4 * 4 + 1) * 8 + eg];
        vf4 wv2 = wl4[(d4 * 4 + 2) * 8 + eg];
        vf4 wv3 = wl4[(d4 * 4 + 3) * 8 + eg];
        #pragma unroll
        for (int rr = 0; rr < 4; ++rr) {
            vf4 xv = __builtin_nontemporal_load(&x0[rr * (DIN / 4) + d4]);
            acc[rr][0] += xv.x * wv0.x + xv.y * wv1.x + xv.z * wv2.x + xv.w * wv3.x;
            acc[rr][1] += xv.x * wv0.y + xv.y * wv1.y + xv.z * wv2.y + xv.w * wv3.y;
            acc[rr][2] += xv.x * wv0.z + xv.y * wv1.z + xv.z * wv2.z + xv.w * wv3.z;
            acc[rr][3] += xv.x * wv0.w + xv.y * wv1.w + xv.z * wv2.w + xv.w * wv3.w;
        }
    }
    #pragma unroll
    for (int rr = 0; rr < 4; ++rr) {
        uint2 packed;
        packed.x = f2bfu(acc[rr][0]) | (f2bfu(acc[rr][1]) << 16);
        packed.y = f2bfu(acc[rr][2]) | (f2bfu(acc[rr][3]) << 16);
        *(uint2*)(h + (size_t)(r0 + rr) * DOUT + eg * 4) = packed;
    }
}

// ---------------- K2: zero cursor[N] + oflow_cnt ----------------------------
__global__ void zero_kernel(int* __restrict__ p, int n) {
    int i = blockIdx.x * 256 + threadIdx.x;
    if (i < n) p[i] = 0;
}

// ---------------- K3: bucketed edge fill (replaces hist+scan+fill) ----------
// slot = atomicAdd(cursor[r]); row-major buckets of stride MBKT. Rows that
// exceed MBKT spill to a tiny overflow list (statistically never happens for
// Poisson(16) degrees; handled in agg for correctness on any input).
__global__ void fill_bucket_kernel(
    const int* __restrict__ row, const int* __restrict__ col,
    const float* __restrict__ val, int* __restrict__ cursor,
    int* __restrict__ bcol, float* __restrict__ bval,
    int* __restrict__ ocnt, int* __restrict__ orow,
    int* __restrict__ ocol, float* __restrict__ oval, int E)
{
    int i = blockIdx.x * 256 + threadIdx.x;
    if (i >= E) return;
    int r = row[i];
    int p = atomicAdd(&cursor[r], 1);
    if (p < MBKT) {
        bcol[r * MBKT + p] = col[i];
        bval[r * MBKT + p] = val[i];
    } else {
        int q = atomicAdd(ocnt, 1);
        if (q < OCAP) {
            orow[q] = r;
            ocol[q] = col[i];
            oval[q] = val[i];
        }
    }
}

// ---------------- K4: per-node gather-accumulate + ReLU ----------------------
// 2 nodes/block, 128 threads (2 waves) per node, uint4 (8 bf16) per thread.
// Edge (col,val) lists loaded ONCE per wave into lane registers (MBKT==64),
// broadcast per-edge via shfl -> gather addresses are pure VALU, no dependent
// scalar-load chain; unroll lets multiple gathers fly.
__global__ __launch_bounds__(256) void agg_kernel(
    const unsigned short* __restrict__ h, const int* __restrict__ cursor,
    const int* __restrict__ bcol, const float* __restrict__ bval,
    const int* __restrict__ ocnt, const int* __restrict__ orow,
    const int* __restrict__ ocol, const float* __restrict__ oval,
    float* __restrict__ out)
{
    const int tid  = threadIdx.x;
    const int half = tid >> 7;
    const int lt   = tid & 127;          // owns 8 floats of the 1024-vector
    const int lane = tid & 63;
    const int r    = blockIdx.x * 2 + half;

    const int deg  = cursor[r];
    const int degb = deg < MBKT ? deg : MBKT;

    // one coalesced load of the whole edge list into lane registers
    int   ec = 0;
    float ev = 0.f;
    if (lane < degb) {
        ec = bcol[r * MBKT + lane];
        ev = bval[r * MBKT + lane];
    }

    float acc[8];
    #pragma unroll
    for (int q = 0; q < 8; ++q) acc[q] = 0.f;

    #pragma unroll 4
    for (int j = 0; j < degb; ++j) {
        int   c = __shfl(ec, j, 64);
        float v = __shfl(ev, j, 64);
        vu4 p = *(const vu4*)(h + (size_t)c * NVEC + lt * 8);
        acc[0] += v * bfu2f(p.x & 0xffffu);
        acc[1] += v * bfu2f(p.x >> 16);
        acc[2] += v * bfu2f(p.y & 0xffffu);
        acc[3] += v * bfu2f(p.y >> 16);
        acc[4] += v * bfu2f(p.z & 0xffffu);
        acc[5] += v * bfu2f(p.z >> 16);
        acc[6] += v * bfu2f(p.w & 0xffffu);
        acc[7] += v * bfu2f(p.w >> 16);
    }

    // cold overflow path: only taken if some row exceeded MBKT slots
    int on = *ocnt;
    if (on > 0) {
        if (on > OCAP) on = OCAP;
        for (int q = 0; q < on; ++q) {
            if (orow[q] == r) {
                int   c = ocol[q];
                float v = oval[q];
                vu4 p = *(const vu4*)(h + (size_t)c * NVEC + lt * 8);
                acc[0] += v * bfu2f(p.x & 0xffffu);
                acc[1] += v * bfu2f(p.x >> 16);
                acc[2] += v * bfu2f(p.y & 0xffffu);
                acc[3] += v * bfu2f(p.y >> 16);
                acc[4] += v * bfu2f(p.z & 0xffffu);
                acc[5] += v * bfu2f(p.z >> 16);
                acc[6] += v * bfu2f(p.w & 0xffffu);
                acc[7] += v * bfu2f(p.w >> 16);
            }
        }
    }

    vf4 o0, o1;
    o0.x = fmaxf(acc[0], 0.f); o0.y = fmaxf(acc[1], 0.f);
    o0.z = fmaxf(acc[2], 0.f); o0.w = fmaxf(acc[3], 0.f);
    o1.x = fmaxf(acc[4], 0.f); o1.y = fmaxf(acc[5], 0.f);
    o1.z = fmaxf(acc[6], 0.f); o1.w = fmaxf(acc[7], 0.f);
    vf4* orow4 = (vf4*)out + (size_t)r * NV4 + lt * 2;
    __builtin_nontemporal_store(o0, &orow4[0]);   // out never re-read: bypass L2
    __builtin_nontemporal_store(o1, &orow4[1]);
}

extern "C" void kernel_launch(void* const* d_in, const int* in_sizes, int n_in,
                              void* d_out, int out_size, void* d_ws, size_t ws_size,
                              hipStream_t stream)
{
    const float* x    = (const float*)d_in[0];
    const float* w    = (const float*)d_in[1];
    const int*   erow = (const int*)d_in[2];
    const int*   ecol = (const int*)d_in[3];
    const float* eval = (const float*)d_in[4];
    float* out = (float*)d_out;

    const int E = in_sizes[2];
    const int N = in_sizes[0] / (KK * DIN);
    const int R = N * KK;

    char* ws = (char*)d_ws;
    size_t off = 0;
    auto take = [&](size_t bytes) {
        void* p = ws + off;
        off += (bytes + 15) & ~(size_t)15;
        return p;
    };
    unsigned short* h = (unsigned short*)take((size_t)R * DOUT * sizeof(unsigned short));
    int*   cursor = (int*)take((size_t)(N + 1) * sizeof(int)); // [N]=oflow_cnt
    int*   bcol   = (int*)take((size_t)N * MBKT * sizeof(int));
    float* bval   = (float*)take((size_t)N * MBKT * sizeof(float));
    int*   orow   = (int*)take((size_t)OCAP * sizeof(int));
    int*   ocol   = (int*)take((size_t)OCAP * sizeof(int));
    float* oval   = (float*)take((size_t)OCAP * sizeof(float));
    int*   ocnt   = cursor + N;
    (void)ws_size;

    gemm_kernel<<<R / 128, 256, 0, stream>>>(x, w, h);
    zero_kernel<<<(N + 1 + 255) / 256, 256, 0, stream>>>(cursor, N + 1);
    fill_bucket_kernel<<<(E + 255) / 256, 256, 0, stream>>>(
        erow, ecol, eval, cursor, bcol, bval, ocnt, orow, ocol, oval, E);
    agg_kernel<<<N / 2, 256, 0, stream>>>(
        h, cursor, bcol, bval, ocnt, orow, ocol, oval, out);
}

// Round 4
// 314.863 us; speedup vs baseline: 1.2003x; 1.2003x over previous
//
#include <hip/hip_runtime.h>
#include <hip/hip_bf16.h>

#define KK 32
#define DIN 128
#define DOUT 32
#define NVEC (KK * DOUT)        // 1024 floats per node
#define NV4  (NVEC / 4)         // 256 float4 per node
#define MBKT 64                 // bucket slots per row == wave size
#define OCAP 4096               // overflow capacity (never used for Poisson(16))
#define TROWS 128               // gemm rows per block

typedef float        vf4 __attribute__((ext_vector_type(4)));
typedef unsigned int vu4 __attribute__((ext_vector_type(4)));

__device__ __forceinline__ float bfu2f(unsigned int u) {
    return __uint_as_float(u << 16);
}
__device__ __forceinline__ unsigned int f2bfu(float f) {
    __hip_bfloat16 b = __float2bfloat16(f);
    return *(unsigned short*)&b;
}

// ---------------- K1: h = x @ W, bf16 out ------------------------------------
// Block: 256 threads, 128 rows. x tile staged in LDS via lane-contiguous
// float4 loads (full 64B lines consumed per instruction). Compute: 4 rows x
// 4 cols per thread. x LDS granules XOR-swizzled by (row>>2)&7 so the 8
// row-quad lanes of a wave hit 8 distinct bank groups (conflict-free; the
// linear layout would be 8-way conflicted: stride 2KB == bank 0).
__global__ __launch_bounds__(256) void gemm_kernel(
    const float* __restrict__ x, const float* __restrict__ w,
    unsigned short* __restrict__ h)
{
    __shared__ vf4 xl[TROWS * 32];        // 64 KB: 128 rows x 32 granules
    __shared__ vf4 wl[DIN * DOUT / 4];    // 16 KB
    const int tid = threadIdx.x;

    // stage W (linear)
    const vf4* w4 = (const vf4*)w;
    #pragma unroll
    for (int i = tid; i < DIN * DOUT / 4; i += 256) wl[i] = w4[i];

    // stage x tile (coalesced 16B/lane; swizzled dst)
    const vf4* x4 = (const vf4*)x + (size_t)blockIdx.x * (TROWS * 32);
    #pragma unroll
    for (int k = 0; k < (TROWS * 32) / 256; ++k) {
        int f = tid + k * 256;            // flat granule index
        int r = f >> 5;
        int g = f & 31;
        xl[r * 32 + (g ^ ((r >> 2) & 7))] = x4[f];
    }
    __syncthreads();

    const int eg  = tid & 7;              // 4-col group
    const int rg  = tid >> 3;             // row-quad 0..31
    const int rg8 = rg & 7;               // swizzle key within wave
    const int r0  = blockIdx.x * TROWS + rg * 4;

    float acc[4][4];
    #pragma unroll
    for (int a = 0; a < 4; ++a)
        #pragma unroll
        for (int b = 0; b < 4; ++b) acc[a][b] = 0.f;

    #pragma unroll 2
    for (int d4 = 0; d4 < DIN / 4; ++d4) {
        vf4 wv0 = wl[(d4 * 4 + 0) * 8 + eg];
        vf4 wv1 = wl[(d4 * 4 + 1) * 8 + eg];
        vf4 wv2 = wl[(d4 * 4 + 2) * 8 + eg];
        vf4 wv3 = wl[(d4 * 4 + 3) * 8 + eg];
        #pragma unroll
        for (int rr = 0; rr < 4; ++rr) {
            vf4 xv = xl[(rg * 4 + rr) * 32 + (d4 ^ rg8)];
            acc[rr][0] += xv.x * wv0.x + xv.y * wv1.x + xv.z * wv2.x + xv.w * wv3.x;
            acc[rr][1] += xv.x * wv0.y + xv.y * wv1.y + xv.z * wv2.y + xv.w * wv3.y;
            acc[rr][2] += xv.x * wv0.z + xv.y * wv1.z + xv.z * wv2.z + xv.w * wv3.z;
            acc[rr][3] += xv.x * wv0.w + xv.y * wv1.w + xv.z * wv2.w + xv.w * wv3.w;
        }
    }
    #pragma unroll
    for (int rr = 0; rr < 4; ++rr) {
        uint2 packed;
        packed.x = f2bfu(acc[rr][0]) | (f2bfu(acc[rr][1]) << 16);
        packed.y = f2bfu(acc[rr][2]) | (f2bfu(acc[rr][3]) << 16);
        *(uint2*)(h + (size_t)(r0 + rr) * DOUT + eg * 4) = packed;
    }
}

// ---------------- K2: zero cursor[N] + oflow_cnt ----------------------------
__global__ void zero_kernel(int* __restrict__ p, int n) {
    int i = blockIdx.x * 256 + threadIdx.x;
    if (i < n) p[i] = 0;
}

// ---------------- K3: bucketed edge fill ------------------------------------
// (col,val) packed into one uint2 -> single 8B scattered store per edge.
__global__ void fill_bucket_kernel(
    const int* __restrict__ row, const int* __restrict__ col,
    const float* __restrict__ val, int* __restrict__ cursor,
    uint2* __restrict__ bedge,
    int* __restrict__ ocnt, int* __restrict__ orow,
    int* __restrict__ ocol, float* __restrict__ oval, int E)
{
    int i = blockIdx.x * 256 + threadIdx.x;
    if (i >= E) return;
    int r = row[i];
    int p = atomicAdd(&cursor[r], 1);
    if (p < MBKT) {
        uint2 e;
        e.x = (unsigned int)col[i];
        e.y = __float_as_uint(val[i]);
        bedge[r * MBKT + p] = e;
    } else {
        int q = atomicAdd(ocnt, 1);
        if (q < OCAP) {
            orow[q] = r;
            ocol[q] = col[i];
            oval[q] = val[i];
        }
    }
}

// ---------------- K4: per-node gather-accumulate + ReLU ----------------------
// 2 nodes/block, 128 threads (2 waves) per node, uint4 (8 bf16) per thread.
// Edge list loaded once per wave into lane registers, broadcast via shfl:
// gather addresses are pure VALU -> multiple gathers in flight per unroll.
__global__ __launch_bounds__(256) void agg_kernel(
    const unsigned short* __restrict__ h, const int* __restrict__ cursor,
    const uint2* __restrict__ bedge,
    const int* __restrict__ ocnt, const int* __restrict__ orow,
    const int* __restrict__ ocol, const float* __restrict__ oval,
    float* __restrict__ out)
{
    const int tid  = threadIdx.x;
    const int half = tid >> 7;
    const int lt   = tid & 127;          // owns 8 floats of the 1024-vector
    const int lane = tid & 63;
    const int r    = blockIdx.x * 2 + half;

    const int deg  = cursor[r];
    const int degb = deg < MBKT ? deg : MBKT;

    int   ec = 0;
    float ev = 0.f;
    if (lane < degb) {
        uint2 e = bedge[r * MBKT + lane];
        ec = (int)e.x;
        ev = __uint_as_float(e.y);
    }

    float acc[8];
    #pragma unroll
    for (int q = 0; q < 8; ++q) acc[q] = 0.f;

    #pragma unroll 4
    for (int j = 0; j < degb; ++j) {
        int   c = __shfl(ec, j, 64);
        float v = __shfl(ev, j, 64);
        vu4 p = *(const vu4*)(h + (size_t)c * NVEC + lt * 8);
        acc[0] += v * bfu2f(p.x & 0xffffu);
        acc[1] += v * bfu2f(p.x >> 16);
        acc[2] += v * bfu2f(p.y & 0xffffu);
        acc[3] += v * bfu2f(p.y >> 16);
        acc[4] += v * bfu2f(p.z & 0xffffu);
        acc[5] += v * bfu2f(p.z >> 16);
        acc[6] += v * bfu2f(p.w & 0xffffu);
        acc[7] += v * bfu2f(p.w >> 16);
    }

    // cold overflow path (correctness only; empty for this graph)
    int on = *ocnt;
    if (on > 0) {
        if (on > OCAP) on = OCAP;
        for (int q = 0; q < on; ++q) {
            if (orow[q] == r) {
                int   c = ocol[q];
                float v = oval[q];
                vu4 p = *(const vu4*)(h + (size_t)c * NVEC + lt * 8);
                acc[0] += v * bfu2f(p.x & 0xffffu);
                acc[1] += v * bfu2f(p.x >> 16);
                acc[2] += v * bfu2f(p.y & 0xffffu);
                acc[3] += v * bfu2f(p.y >> 16);
                acc[4] += v * bfu2f(p.z & 0xffffu);
                acc[5] += v * bfu2f(p.z >> 16);
                acc[6] += v * bfu2f(p.w & 0xffffu);
                acc[7] += v * bfu2f(p.w >> 16);
            }
        }
    }

    vf4 o0, o1;
    o0.x = fmaxf(acc[0], 0.f); o0.y = fmaxf(acc[1], 0.f);
    o0.z = fmaxf(acc[2], 0.f); o0.w = fmaxf(acc[3], 0.f);
    o1.x = fmaxf(acc[4], 0.f); o1.y = fmaxf(acc[5], 0.f);
    o1.z = fmaxf(acc[6], 0.f); o1.w = fmaxf(acc[7], 0.f);
    vf4* op = (vf4*)out + (size_t)r * NV4 + lt * 2;
    __builtin_nontemporal_store(o0, &op[0]);   // out never re-read
    __builtin_nontemporal_store(o1, &op[1]);
}

extern "C" void kernel_launch(void* const* d_in, const int* in_sizes, int n_in,
                              void* d_out, int out_size, void* d_ws, size_t ws_size,
                              hipStream_t stream)
{
    const float* x    = (const float*)d_in[0];
    const float* w    = (const float*)d_in[1];
    const int*   erow = (const int*)d_in[2];
    const int*   ecol = (const int*)d_in[3];
    const float* eval = (const float*)d_in[4];
    float* out = (float*)d_out;

    const int E = in_sizes[2];
    const int N = in_sizes[0] / (KK * DIN);
    const int R = N * KK;

    char* ws = (char*)d_ws;
    size_t off = 0;
    auto take = [&](size_t bytes) {
        void* p = ws + off;
        off += (bytes + 15) & ~(size_t)15;
        return p;
    };
    unsigned short* h = (unsigned short*)take((size_t)R * DOUT * sizeof(unsigned short));
    int*   cursor = (int*)take((size_t)(N + 1) * sizeof(int)); // [N]=oflow_cnt
    uint2* bedge  = (uint2*)take((size_t)N * MBKT * sizeof(uint2));
    int*   orow   = (int*)take((size_t)OCAP * sizeof(int));
    int*   ocol   = (int*)take((size_t)OCAP * sizeof(int));
    float* oval   = (float*)take((size_t)OCAP * sizeof(float));
    int*   ocnt   = cursor + N;
    (void)ws_size;

    gemm_kernel<<<R / TROWS, 256, 0, stream>>>(x, w, h);
    zero_kernel<<<(N + 1 + 255) / 256, 256, 0, stream>>>(cursor, N + 1);
    fill_bucket_kernel<<<(E + 255) / 256, 256, 0, stream>>>(
        erow, ecol, eval, cursor, bedge, ocnt, orow, ocol, oval, E);
    agg_kernel<<<N / 2, 256, 0, stream>>>(
        h, cursor, bedge, ocnt, orow, ocol, oval, out);
}

// Round 5
// 305.903 us; speedup vs baseline: 1.2355x; 1.0293x over previous
//
#include <hip/hip_runtime.h>
#include <hip/hip_bf16.h>

#define KK 32
#define DIN 128
#define DOUT 32
#define NVEC (KK * DOUT)        // 1024 floats per node
#define NV4  (NVEC / 4)         // 256 float4 per node
#define MBKT 64                 // bucket slots per row == wave size
#define OCAP 4096               // overflow capacity (never used for Poisson(16))

typedef float        vf4   __attribute__((ext_vector_type(4)));
typedef unsigned int vu4   __attribute__((ext_vector_type(4)));
typedef short        bf16x8 __attribute__((ext_vector_type(8)));

__device__ __forceinline__ float bfu2f(unsigned int u) {
    return __uint_as_float(u << 16);
}
__device__ __forceinline__ unsigned int f2bfu(float f) {
    __hip_bfloat16 b = __float2bfloat16(f);
    return *(unsigned short*)&b;
}

// ---------------- K1: h = x @ W via bf16 MFMA, bf16 out ----------------------
// 16x16x32 MFMA. A loaded straight from global in fragment layout
// (A[m=lane&15][k=(lane>>4)*8+j]): lanes {l,l+16,l+32,l+48} cover one row's
// 128B k-span -> every 64B line fully consumed, no LDS staging of x.
// B (W, 16KB, L2-hot) pre-packed into registers: B[k=(lane>>4)*8+j][n=lane&15].
// C/D layout (col=lane&15, row=(lane>>4)*4+reg) repacked to standard h[R][32]
// through a per-wave LDS buffer (rows padded to 33 f32 -> conflict-free).
// Grid 2500 x 256: wave_gid in [0,10000), exactly 2 row-tiles of 16 each.
__global__ __launch_bounds__(256) void gemm_kernel(
    const float* __restrict__ x, const float* __restrict__ w,
    unsigned short* __restrict__ h)
{
    __shared__ float cbuf[4][16 * 33];    // 8448 B: per-wave repack buffers
    const int tid  = threadIdx.x;
    const int lane = tid & 63;
    const int wid  = tid >> 6;
    const int q    = lane >> 4;           // quad 0..3
    const int lm   = lane & 15;

    // ---- B fragments: 2 n-tiles x 4 k-steps, packed once ----
    bf16x8 bf[2][4];
    #pragma unroll
    for (int nt = 0; nt < 2; ++nt) {
        #pragma unroll
        for (int ks = 0; ks < 4; ++ks) {
            bf16x8 f;
            #pragma unroll
            for (int j = 0; j < 8; ++j) {
                int k = ks * 32 + q * 8 + j;
                f[j] = (short)f2bfu(w[k * DOUT + nt * 16 + lm]);
            }
            bf[nt][ks] = f;
        }
    }

    const int wgid = blockIdx.x * 4 + wid;
    float* cb = &cbuf[wid][0];

    #pragma unroll
    for (int it = 0; it < 2; ++it) {
        const int tile = wgid * 2 + it;   // 0..19999
        const int r0   = tile * 16;
        const float* xrow = x + (size_t)(r0 + lm) * DIN + q * 8;

        vf4 acc0 = {0.f, 0.f, 0.f, 0.f};
        vf4 acc1 = {0.f, 0.f, 0.f, 0.f};

        #pragma unroll
        for (int ks = 0; ks < 4; ++ks) {
            vf4 a0 = *(const vf4*)(xrow + ks * 32);
            vf4 a1 = *(const vf4*)(xrow + ks * 32 + 4);
            bf16x8 af;
            af[0] = (short)f2bfu(a0.x); af[1] = (short)f2bfu(a0.y);
            af[2] = (short)f2bfu(a0.z); af[3] = (short)f2bfu(a0.w);
            af[4] = (short)f2bfu(a1.x); af[5] = (short)f2bfu(a1.y);
            af[6] = (short)f2bfu(a1.z); af[7] = (short)f2bfu(a1.w);
            acc0 = __builtin_amdgcn_mfma_f32_16x16x32_bf16(af, bf[0][ks], acc0, 0, 0, 0);
            acc1 = __builtin_amdgcn_mfma_f32_16x16x32_bf16(af, bf[1][ks], acc1, 0, 0, 0);
        }

        // ---- repack C-layout -> standard via per-wave LDS ----
        #pragma unroll
        for (int q2 = 0; q2 < 4; ++q2) {
            int row = q * 4 + q2;         // C/D: row=(lane>>4)*4+reg
            cb[row * 33 + lm]      = acc0[q2];
            cb[row * 33 + 16 + lm] = acc1[q2];
        }
        __syncthreads();                  // uniform trip count: all waves do 2 iters

        const int rr = lane >> 2;         // 16 rows, 4 lanes each
        const int cs = (lane & 3) * 8;    // 8-col segment
        const float* src = cb + rr * 33 + cs;
        vu4 packed;
        packed.x = f2bfu(src[0]) | (f2bfu(src[1]) << 16);
        packed.y = f2bfu(src[2]) | (f2bfu(src[3]) << 16);
        packed.z = f2bfu(src[4]) | (f2bfu(src[5]) << 16);
        packed.w = f2bfu(src[6]) | (f2bfu(src[7]) << 16);
        *(vu4*)(h + (size_t)(r0 + rr) * DOUT + cs) = packed;
        __syncthreads();                  // protect cbuf before next iter's writes
    }
}

// ---------------- K2: zero cursor[N] + oflow_cnt ----------------------------
__global__ void zero_kernel(int* __restrict__ p, int n) {
    int i = blockIdx.x * 256 + threadIdx.x;
    if (i < n) p[i] = 0;
}

// ---------------- K3: bucketed edge fill ------------------------------------
__global__ void fill_bucket_kernel(
    const int* __restrict__ row, const int* __restrict__ col,
    const float* __restrict__ val, int* __restrict__ cursor,
    uint2* __restrict__ bedge,
    int* __restrict__ ocnt, int* __restrict__ orow,
    int* __restrict__ ocol, float* __restrict__ oval, int E)
{
    int i = blockIdx.x * 256 + threadIdx.x;
    if (i >= E) return;
    int r = row[i];
    int p = atomicAdd(&cursor[r], 1);
    if (p < MBKT) {
        uint2 e;
        e.x = (unsigned int)col[i];
        e.y = __float_as_uint(val[i]);
        bedge[r * MBKT + p] = e;
    } else {
        int q = atomicAdd(ocnt, 1);
        if (q < OCAP) {
            orow[q] = r;
            ocol[q] = col[i];
            oval[q] = val[i];
        }
    }
}

// ---------------- K4: per-node gather-accumulate + ReLU ----------------------
__global__ __launch_bounds__(256) void agg_kernel(
    const unsigned short* __restrict__ h, const int* __restrict__ cursor,
    const uint2* __restrict__ bedge,
    const int* __restrict__ ocnt, const int* __restrict__ orow,
    const int* __restrict__ ocol, const float* __restrict__ oval,
    float* __restrict__ out)
{
    const int tid  = threadIdx.x;
    const int half = tid >> 7;
    const int lt   = tid & 127;          // owns 8 floats of the 1024-vector
    const int lane = tid & 63;
    const int r    = blockIdx.x * 2 + half;

    const int deg  = cursor[r];
    const int degb = deg < MBKT ? deg : MBKT;

    int   ec = 0;
    float ev = 0.f;
    if (lane < degb) {
        uint2 e = bedge[r * MBKT + lane];
        ec = (int)e.x;
        ev = __uint_as_float(e.y);
    }

    float acc[8];
    #pragma unroll
    for (int q = 0; q < 8; ++q) acc[q] = 0.f;

    #pragma unroll 4
    for (int j = 0; j < degb; ++j) {
        int   c = __shfl(ec, j, 64);
        float v = __shfl(ev, j, 64);
        vu4 p = *(const vu4*)(h + (size_t)c * NVEC + lt * 8);
        acc[0] += v * bfu2f(p.x & 0xffffu);
        acc[1] += v * bfu2f(p.x >> 16);
        acc[2] += v * bfu2f(p.y & 0xffffu);
        acc[3] += v * bfu2f(p.y >> 16);
        acc[4] += v * bfu2f(p.z & 0xffffu);
        acc[5] += v * bfu2f(p.z >> 16);
        acc[6] += v * bfu2f(p.w & 0xffffu);
        acc[7] += v * bfu2f(p.w >> 16);
    }

    // cold overflow path (correctness only; empty for this graph)
    int on = *ocnt;
    if (on > 0) {
        if (on > OCAP) on = OCAP;
        for (int q = 0; q < on; ++q) {
            if (orow[q] == r) {
                int   c = ocol[q];
                float v = oval[q];
                vu4 p = *(const vu4*)(h + (size_t)c * NVEC + lt * 8);
                acc[0] += v * bfu2f(p.x & 0xffffu);
                acc[1] += v * bfu2f(p.x >> 16);
                acc[2] += v * bfu2f(p.y & 0xffffu);
                acc[3] += v * bfu2f(p.y >> 16);
                acc[4] += v * bfu2f(p.z & 0xffffu);
                acc[5] += v * bfu2f(p.z >> 16);
                acc[6] += v * bfu2f(p.w & 0xffffu);
                acc[7] += v * bfu2f(p.w >> 16);
            }
        }
    }

    vf4 o0, o1;
    o0.x = fmaxf(acc[0], 0.f); o0.y = fmaxf(acc[1], 0.f);
    o0.z = fmaxf(acc[2], 0.f); o0.w = fmaxf(acc[3], 0.f);
    o1.x = fmaxf(acc[4], 0.f); o1.y = fmaxf(acc[5], 0.f);
    o1.z = fmaxf(acc[6], 0.f); o1.w = fmaxf(acc[7], 0.f);
    vf4* op = (vf4*)out + (size_t)r * NV4 + lt * 2;
    __builtin_nontemporal_store(o0, &op[0]);   // out never re-read
    __builtin_nontemporal_store(o1, &op[1]);
}

extern "C" void kernel_launch(void* const* d_in, const int* in_sizes, int n_in,
                              void* d_out, int out_size, void* d_ws, size_t ws_size,
                              hipStream_t stream)
{
    const float* x    = (const float*)d_in[0];
    const float* w    = (const float*)d_in[1];
    const int*   erow = (const int*)d_in[2];
    const int*   ecol = (const int*)d_in[3];
    const float* eval = (const float*)d_in[4];
    float* out = (float*)d_out;

    const int E = in_sizes[2];
    const int N = in_sizes[0] / (KK * DIN);
    const int R = N * KK;

    char* ws = (char*)d_ws;
    size_t off = 0;
    auto take = [&](size_t bytes) {
        void* p = ws + off;
        off += (bytes + 15) & ~(size_t)15;
        return p;
    };
    unsigned short* h = (unsigned short*)take((size_t)R * DOUT * sizeof(unsigned short));
    int*   cursor = (int*)take((size_t)(N + 1) * sizeof(int)); // [N]=oflow_cnt
    uint2* bedge  = (uint2*)take((size_t)N * MBKT * sizeof(uint2));
    int*   orow   = (int*)take((size_t)OCAP * sizeof(int));
    int*   ocol   = (int*)take((size_t)OCAP * sizeof(int));
    float* oval   = (float*)take((size_t)OCAP * sizeof(float));
    int*   ocnt   = cursor + N;
    (void)ws_size;

    // R/16 row-tiles, 2 per wave: grid = R/128 blocks of 4 waves
    gemm_kernel<<<R / 128, 256, 0, stream>>>(x, w, h);
    zero_kernel<<<(N + 1 + 255) / 256, 256, 0, stream>>>(cursor, N + 1);
    fill_bucket_kernel<<<(E + 255) / 256, 256, 0, stream>>>(
        erow, ecol, eval, cursor, bedge, ocnt, orow, ocol, oval, E);
    agg_kernel<<<N / 2, 256, 0, stream>>>(
        h, cursor, bedge, ocnt, orow, ocol, oval, out);
}

// Round 6
// 302.597 us; speedup vs baseline: 1.2490x; 1.0109x over previous
//
#include <hip/hip_runtime.h>
#include <hip/hip_bf16.h>

#define KK 32
#define DIN 128
#define DOUT 32
#define NVEC (KK * DOUT)        // 1024 floats per node
#define MBKT 64                 // bucket slots per row == wave size
#define OCAP 4096               // overflow capacity (never used for Poisson(16))

typedef float        vf4    __attribute__((ext_vector_type(4)));
typedef unsigned int vu4    __attribute__((ext_vector_type(4)));
typedef short        bf16x8 __attribute__((ext_vector_type(8)));

__device__ __forceinline__ float bfu2f(unsigned int u) {
    return __uint_as_float(u << 16);
}
__device__ __forceinline__ unsigned int f2bfu(float f) {
    __hip_bfloat16 b = __float2bfloat16(f);
    return *(unsigned short*)&b;
}

// ---------------- K1 (fused): fill_bucket (blocks < FB) + MFMA gemm ----------
// gemm: 16x16x32 bf16 MFMA, A straight from global in fragment layout, B (W)
// packed once per wave (16KB W is L1-resident after first wave). C stored
// DIRECTLY from fragments -- no LDS repack, no __syncthreads -- into a
// column-permuted h layout: h[r][2c]=col c, h[r][2c+1]=col c+16. Lane l
// (q=l>>4, lm=l&15) stores one packed dword (2 bf16) per reg q2 at row
// q*4+q2, byte offset lm*4: per instruction 4 rows x 64B contiguous.
// agg reads whole h rows (layout-agnostic); out-write unpermutes (see K3).
// 1 tile (16 rows) per wave: 20000 waves -> full TLP for latency hiding.
__global__ __launch_bounds__(256) void gemm_fill_kernel(
    const float* __restrict__ x, const float* __restrict__ w,
    unsigned short* __restrict__ h,
    const int* __restrict__ erow, const int* __restrict__ ecol,
    const float* __restrict__ eval, int* __restrict__ cursor,
    uint2* __restrict__ bedge,
    int* __restrict__ ocnt, int* __restrict__ orow,
    int* __restrict__ ocol, float* __restrict__ oval,
    int E, int FB)
{
    const int tid = threadIdx.x;

    if (blockIdx.x < (unsigned)FB) {
        // ---- fill part: first in dispatch queue -> overlaps gemm's start ----
        int i = blockIdx.x * 256 + tid;
        if (i >= E) return;
        int r = erow[i];
        int p = atomicAdd(&cursor[r], 1);
        if (p < MBKT) {
            uint2 e;
            e.x = (unsigned int)ecol[i];
            e.y = __float_as_uint(eval[i]);
            bedge[r * MBKT + p] = e;
        } else {
            int q = atomicAdd(ocnt, 1);
            if (q < OCAP) {
                orow[q] = r;
                ocol[q] = ecol[i];
                oval[q] = eval[i];
            }
        }
        return;
    }

    // ---- gemm part ----
    const int lane = tid & 63;
    const int wid  = tid >> 6;
    const int q    = lane >> 4;           // quad 0..3
    const int lm   = lane & 15;

    // B fragments: 2 n-tiles x 4 k-steps (B[k=q*8+j][n=lm]); W is L1-hot.
    bf16x8 bf[2][4];
    #pragma unroll
    for (int nt = 0; nt < 2; ++nt) {
        #pragma unroll
        for (int ks = 0; ks < 4; ++ks) {
            bf16x8 f;
            #pragma unroll
            for (int j = 0; j < 8; ++j) {
                int k = ks * 32 + q * 8 + j;
                f[j] = (short)f2bfu(w[k * DOUT + nt * 16 + lm]);
            }
            bf[nt][ks] = f;
        }
    }

    const int tile = (blockIdx.x - FB) * 4 + wid;   // 0..19999
    const int r0   = tile * 16;
    const float* xrow = x + (size_t)(r0 + lm) * DIN + q * 8;

    vf4 acc0 = {0.f, 0.f, 0.f, 0.f};
    vf4 acc1 = {0.f, 0.f, 0.f, 0.f};

    #pragma unroll
    for (int ks = 0; ks < 4; ++ks) {
        vf4 a0 = *(const vf4*)(xrow + ks * 32);
        vf4 a1 = *(const vf4*)(xrow + ks * 32 + 4);
        bf16x8 af;
        af[0] = (short)f2bfu(a0.x); af[1] = (short)f2bfu(a0.y);
        af[2] = (short)f2bfu(a0.z); af[3] = (short)f2bfu(a0.w);
        af[4] = (short)f2bfu(a1.x); af[5] = (short)f2bfu(a1.y);
        af[6] = (short)f2bfu(a1.z); af[7] = (short)f2bfu(a1.w);
        acc0 = __builtin_amdgcn_mfma_f32_16x16x32_bf16(af, bf[0][ks], acc0, 0, 0, 0);
        acc1 = __builtin_amdgcn_mfma_f32_16x16x32_bf16(af, bf[1][ks], acc1, 0, 0, 0);
    }

    // direct C store: row=(lane>>4)*4+q2 (C/D mapping), permuted cols
    #pragma unroll
    for (int q2 = 0; q2 < 4; ++q2) {
        unsigned int pk = f2bfu(acc0[q2]) | (f2bfu(acc1[q2]) << 16);
        *(unsigned int*)(h + (size_t)(r0 + q * 4 + q2) * DOUT + lm * 2) = pk;
    }
}

// ---------------- K2: zero cursor[N] + oflow_cnt ----------------------------
__global__ void zero_kernel(int* __restrict__ p, int n) {
    int i = blockIdx.x * 256 + threadIdx.x;
    if (i < n) p[i] = 0;
}

// ---------------- K3: per-node gather-accumulate + ReLU ----------------------
// h rows are column-permuted (see K1): position p within a 32-col group maps
// to true col (p>>1) + 16*(p&1). Lane lt's 8 positions (k=lt>>2, p=8*(lt&3)+i)
// -> even i = cols 4*(lt&3)+i/2, odd i = cols 16+4*(lt&3)+i/2. Out write
// unpermutes into two coalesced dwordx4 stores.
__global__ __launch_bounds__(256) void agg_kernel(
    const unsigned short* __restrict__ h, const int* __restrict__ cursor,
    const uint2* __restrict__ bedge,
    const int* __restrict__ ocnt, const int* __restrict__ orow,
    const int* __restrict__ ocol, const float* __restrict__ oval,
    float* __restrict__ out)
{
    const int tid  = threadIdx.x;
    const int half = tid >> 7;
    const int lt   = tid & 127;          // owns 8 h-positions (16B)
    const int lane = tid & 63;
    const int r    = blockIdx.x * 2 + half;

    const int deg  = cursor[r];
    const int degb = deg < MBKT ? deg : MBKT;
    const int on0  = *ocnt;              // issued early; cold path below

    int   ec = 0;
    float ev = 0.f;
    if (lane < degb) {
        uint2 e = bedge[r * MBKT + lane];
        ec = (int)e.x;
        ev = __uint_as_float(e.y);
    }

    float acc[8];
    #pragma unroll
    for (int q = 0; q < 8; ++q) acc[q] = 0.f;

    #pragma unroll 4
    for (int j = 0; j < degb; ++j) {
        int   c = __shfl(ec, j, 64);
        float v = __shfl(ev, j, 64);
        vu4 p = *(const vu4*)(h + (size_t)c * NVEC + lt * 8);
        acc[0] += v * bfu2f(p.x & 0xffffu);
        acc[1] += v * bfu2f(p.x >> 16);
        acc[2] += v * bfu2f(p.y & 0xffffu);
        acc[3] += v * bfu2f(p.y >> 16);
        acc[4] += v * bfu2f(p.z & 0xffffu);
        acc[5] += v * bfu2f(p.z >> 16);
        acc[6] += v * bfu2f(p.w & 0xffffu);
        acc[7] += v * bfu2f(p.w >> 16);
    }

    // cold overflow path (correctness only; empty for this graph)
    if (on0 > 0) {
        int on = on0 > OCAP ? OCAP : on0;
        for (int q = 0; q < on; ++q) {
            if (orow[q] == r) {
                int   c = ocol[q];
                float v = oval[q];
                vu4 p = *(const vu4*)(h + (size_t)c * NVEC + lt * 8);
                acc[0] += v * bfu2f(p.x & 0xffffu);
                acc[1] += v * bfu2f(p.x >> 16);
                acc[2] += v * bfu2f(p.y & 0xffffu);
                acc[3] += v * bfu2f(p.y >> 16);
                acc[4] += v * bfu2f(p.z & 0xffffu);
                acc[5] += v * bfu2f(p.z >> 16);
                acc[6] += v * bfu2f(p.w & 0xffffu);
                acc[7] += v * bfu2f(p.w >> 16);
            }
        }
    }

    // unpermute: even accs -> cols 4*(lt&3)..+3 ; odd accs -> +16
    vf4 oA, oB;
    oA.x = fmaxf(acc[0], 0.f); oA.y = fmaxf(acc[2], 0.f);
    oA.z = fmaxf(acc[4], 0.f); oA.w = fmaxf(acc[6], 0.f);
    oB.x = fmaxf(acc[1], 0.f); oB.y = fmaxf(acc[3], 0.f);
    oB.z = fmaxf(acc[5], 0.f); oB.w = fmaxf(acc[7], 0.f);
    float* obase = out + (size_t)r * NVEC + (lt >> 2) * 32 + (lt & 3) * 4;
    __builtin_nontemporal_store(oA, (vf4*)obase);        // cols c..c+3
    __builtin_nontemporal_store(oB, (vf4*)(obase + 16)); // cols 16+c..+3
}

extern "C" void kernel_launch(void* const* d_in, const int* in_sizes, int n_in,
                              void* d_out, int out_size, void* d_ws, size_t ws_size,
                              hipStream_t stream)
{
    const float* x    = (const float*)d_in[0];
    const float* w    = (const float*)d_in[1];
    const int*   erow = (const int*)d_in[2];
    const int*   ecol = (const int*)d_in[3];
    const float* eval = (const float*)d_in[4];
    float* out = (float*)d_out;

    const int E = in_sizes[2];
    const int N = in_sizes[0] / (KK * DIN);
    const int R = N * KK;

    char* ws = (char*)d_ws;
    size_t off = 0;
    auto take = [&](size_t bytes) {
        void* p = ws + off;
        off += (bytes + 15) & ~(size_t)15;
        return p;
    };
    unsigned short* h = (unsigned short*)take((size_t)R * DOUT * sizeof(unsigned short));
    int*   cursor = (int*)take((size_t)(N + 1) * sizeof(int)); // [N]=oflow_cnt
    uint2* bedge  = (uint2*)take((size_t)N * MBKT * sizeof(uint2));
    int*   orow   = (int*)take((size_t)OCAP * sizeof(int));
    int*   ocol   = (int*)take((size_t)OCAP * sizeof(int));
    float* oval   = (float*)take((size_t)OCAP * sizeof(float));
    int*   ocnt   = cursor + N;
    (void)ws_size;

    const int FB = (E + 255) / 256;       // fill blocks (first in queue)
    const int GB = (R / 16) / 4;          // 1 tile/wave, 4 waves/block

    zero_kernel<<<(N + 1 + 255) / 256, 256, 0, stream>>>(cursor, N + 1);
    gemm_fill_kernel<<<FB + GB, 256, 0, stream>>>(
        x, w, h, erow, ecol, eval, cursor, bedge, ocnt, orow, ocol, oval, E, FB);
    agg_kernel<<<N / 2, 256, 0, stream>>>(
        h, cursor, bedge, ocnt, orow, ocol, oval, out);
}